// Round 7
// baseline (3648.632 us; speedup 1.0000x reference)
//
#include <hip/hip_runtime.h>
#include <hip/hip_bf16.h>
#include <stdint.h>

// Problem constants (batch_max_length=25 fixed by harness input).
#define B_   256
#define W_   128
#define CIN_ 512
#define H_   512
#define C_   6625
#define G3_  1536   // 3*H
#define T_   25
#define XH_  7137   // CIN + C

typedef short v8s __attribute__((ext_vector_type(8)));   // 8 bf16 in 4 VGPRs
typedef float v4f __attribute__((ext_vector_type(4)));   // MFMA 16x16 accumulator

__device__ __forceinline__ float bf2f(ushort u){ return __uint_as_float(((uint32_t)u) << 16); }
__device__ __forceinline__ ushort f2bf(float f){
  uint32_t x = __float_as_uint(f);
  x += 0x7fffu + ((x >> 16) & 1u);   // RNE
  return (ushort)(x >> 16);
}
// fast tanh — used ONLY in the attention e-path (errors dilute ~100x via softmax/context).
__device__ __forceinline__ float fast_tanh(float x){
  x = fminf(15.f, fmaxf(-15.f, x));
  float u = __expf(2.f * x);
  return (u - 1.f) * __frcp_rn(u + 1.f);
}

// MFMA 16x16x32 bf16 via inline asm.
// A,B: 8 contiguous bf16 per lane at row (lane&15), k-offset 8*(lane>>4).
// D/C: col = lane&15, row = (lane>>4)*4 + reg  [learn_hip m89].
__device__ __forceinline__ v4f mfma_bf16(v8s a, v8s b, v4f c){
  asm volatile("v_mfma_f32_16x16x32_bf16 %0, %1, %2, %0" : "+v"(c) : "v"(a), "v"(b));
  return c;
}

// ---------------- conversion / packing ----------------

// fp32 -> 2-limb bf16 (hi+lo); rep err ~ x*2^-18
__global__ void cvt_split2(const float* __restrict__ in, ushort* __restrict__ a1,
                           ushort* __restrict__ a2, int n){
  int idx = (blockIdx.x * blockDim.x + threadIdx.x) * 4;
  if (idx < n){
    float4 v = *(const float4*)(in + idx);
    ushort4 h1, h2; float x, r;
    x=v.x; h1.x=f2bf(x); r=x-bf2f(h1.x); h2.x=f2bf(r);
    x=v.y; h1.y=f2bf(x); r=x-bf2f(h1.y); h2.y=f2bf(r);
    x=v.z; h1.z=f2bf(x); r=x-bf2f(h1.z); h2.z=f2bf(r);
    x=v.w; h1.w=f2bf(x); r=x-bf2f(h1.w); h2.w=f2bf(r);
    *(ushort4*)(a1 + idx) = h1;
    *(ushort4*)(a2 + idx) = h2;
  }
}

// fp32 -> 3-limb bf16; 3x8 mantissa bits = fp32-exact (rep err ~ x*2^-27)
__global__ void cvt_split3(const float* __restrict__ in, ushort* __restrict__ a1,
                           ushort* __restrict__ a2, ushort* __restrict__ a3, int n){
  int idx = (blockIdx.x * blockDim.x + threadIdx.x) * 4;
  if (idx < n){
    float4 v = *(const float4*)(in + idx);
    ushort4 h1, h2, h3; float x, r;
    #define SPL(F) x=v.F; h1.F=f2bf(x); r=x-bf2f(h1.F); h2.F=f2bf(r); r-=bf2f(h2.F); h3.F=f2bf(r);
    SPL(x) SPL(y) SPL(z) SPL(w)
    #undef SPL
    *(ushort4*)(a1 + idx) = h1;
    *(ushort4*)(a2 + idx) = h2;
    *(ushort4*)(a3 + idx) = h3;
  }
}

// gru_wih[:, :CIN] -> 3-limb bf16 [G3][CIN]
__global__ void pack_wih_split3(const float* __restrict__ wih, ushort* __restrict__ a1,
                                ushort* __restrict__ a2, ushort* __restrict__ a3){
  int idx = blockIdx.x * 256 + threadIdx.x;       // total G3_*CIN_
  int g = idx >> 9, k = idx & 511;
  float x = wih[(size_t)g * XH_ + k];
  ushort h1 = f2bf(x); float r = x - bf2f(h1);
  ushort h2 = f2bf(r); r -= bf2f(h2);
  a1[idx] = h1; a2[idx] = h2; a3[idx] = f2bf(r);
}

// gru_wih[:, CIN:].T -> fp32 [C][G3] (coalesced per-step one-hot gathers)
__global__ void transpose_oh(const float* __restrict__ wih, float* __restrict__ out){
  __shared__ float t[32][33];
  int c0 = blockIdx.x * 32, g0 = blockIdx.y * 32;
  int tx = threadIdx.x & 31, ty = threadIdx.x >> 5;   // 256 thr = 32x8
  for (int r = ty; r < 32; r += 8){
    int c = c0 + tx;
    t[r][tx] = (c < C_) ? wih[(size_t)(g0 + r) * XH_ + CIN_ + c] : 0.f;
  }
  __syncthreads();
  for (int r = ty; r < 32; r += 8){
    int c = c0 + r;
    if (c < C_) out[(size_t)c * G3_ + (g0 + tx)] = t[tx][r];
  }
}

// -------- GEMMs: C[M,N] = A[M,K] * B[N,K]^T (+bias), fp32 out --------
// 4 waves (2x2); wave tile (WFM*16)x(WFN*16); direct global->register fragments.

// Hproj: A fp32 (split2 on the fly), B split2 pre-packed. 3 products.
template<int WFM, int WFN>
__global__ __launch_bounds__(256, 2) void gemm_hproj(
    const float* __restrict__ A, const ushort* __restrict__ B1,
    const ushort* __restrict__ B2, float* __restrict__ Cout,
    int M, int N, int K)
{
  const int tid = threadIdx.x;
  const int wave = tid >> 6, lane = tid & 63;
  const int wy = wave >> 1, wx = wave & 1;
  const int lrow = lane & 15, kof = (lane >> 4) << 3;
  const int m0 = blockIdx.x * (WFM * 32) + wy * (WFM * 16);
  const int n0 = blockIdx.y * (WFN * 32) + wx * (WFN * 16);

  v4f acc[WFM][WFN];
  #pragma unroll
  for (int i = 0; i < WFM; i++)
    #pragma unroll
    for (int j = 0; j < WFN; j++) acc[i][j] = (v4f)0.f;

  const float* Ap[WFM];
  #pragma unroll
  for (int i = 0; i < WFM; i++) Ap[i] = A + (size_t)(m0 + i * 16 + lrow) * K + kof;
  size_t boff[WFN];
  #pragma unroll
  for (int j = 0; j < WFN; j++) boff[j] = (size_t)(n0 + j * 16 + lrow) * K + kof;

  for (int kk = 0; kk < K; kk += 32){
    v8s a1[WFM], a2[WFM], b1[WFN], b2[WFN];
    #pragma unroll
    for (int i = 0; i < WFM; i++){
      float4 x0 = *(const float4*)(Ap[i] + kk);
      float4 x1 = *(const float4*)(Ap[i] + kk + 4);
      float xs[8] = {x0.x,x0.y,x0.z,x0.w,x1.x,x1.y,x1.z,x1.w};
      #pragma unroll
      for (int q = 0; q < 8; q++){
        ushort h = f2bf(xs[q]);
        a1[i][q] = (short)h;
        a2[i][q] = (short)f2bf(xs[q] - bf2f(h));
      }
    }
    #pragma unroll
    for (int j = 0; j < WFN; j++){
      b1[j] = *(const v8s*)(B1 + boff[j] + kk);
      b2[j] = *(const v8s*)(B2 + boff[j] + kk);
    }
    #pragma unroll
    for (int i = 0; i < WFM; i++)
      #pragma unroll
      for (int j = 0; j < WFN; j++){
        acc[i][j] = mfma_bf16(a1[i], b1[j], acc[i][j]);
        acc[i][j] = mfma_bf16(a1[i], b2[j], acc[i][j]);
        acc[i][j] = mfma_bf16(a2[i], b1[j], acc[i][j]);
      }
  }
  asm volatile("s_nop 7\n\ts_nop 7" ::);

  const int r0 = (lane >> 4) << 2;
  #pragma unroll
  for (int j = 0; j < WFN; j++){
    int col = n0 + j * 16 + lrow;
    #pragma unroll
    for (int i = 0; i < WFM; i++)
      #pragma unroll
      for (int r = 0; r < 4; r++)
        Cout[(size_t)(m0 + i * 16 + r0 + r) * N + col] = acc[i][j][r];
  }
}

// 2-limb split GEMM (err ~1e-6): ph, gen-probs.
template<int WFM, int WFN, bool BIAS>
__global__ __launch_bounds__(256, 2) void gemm_split2(
    const ushort* __restrict__ A1, const ushort* __restrict__ A2,
    const ushort* __restrict__ B1, const ushort* __restrict__ B2,
    float* __restrict__ Cout, const float* __restrict__ bias,
    int M, int N, int K, long long ldc)
{
  const int tid = threadIdx.x;
  const int wave = tid >> 6, lane = tid & 63;
  const int wy = wave >> 1, wx = wave & 1;
  const int lrow = lane & 15, kof = (lane >> 4) << 3;
  const int m0 = blockIdx.x * (WFM * 32) + wy * (WFM * 16);
  const int n0 = blockIdx.y * (WFN * 32) + wx * (WFN * 16);

  v4f acc[WFM][WFN];
  #pragma unroll
  for (int i = 0; i < WFM; i++)
    #pragma unroll
    for (int j = 0; j < WFN; j++) acc[i][j] = (v4f)0.f;

  size_t aoff[WFM], boff[WFN];
  #pragma unroll
  for (int i = 0; i < WFM; i++) aoff[i] = (size_t)(m0 + i * 16 + lrow) * K + kof;
  #pragma unroll
  for (int j = 0; j < WFN; j++){
    int r = n0 + j * 16 + lrow; if (r >= N) r = N - 1;
    boff[j] = (size_t)r * K + kof;
  }

  for (int kk = 0; kk < K; kk += 32){
    v8s a1[WFM], a2[WFM], b1[WFN], b2[WFN];
    #pragma unroll
    for (int i = 0; i < WFM; i++){
      a1[i] = *(const v8s*)(A1 + aoff[i] + kk);
      a2[i] = *(const v8s*)(A2 + aoff[i] + kk);
    }
    #pragma unroll
    for (int j = 0; j < WFN; j++){
      b1[j] = *(const v8s*)(B1 + boff[j] + kk);
      b2[j] = *(const v8s*)(B2 + boff[j] + kk);
    }
    #pragma unroll
    for (int i = 0; i < WFM; i++)
      #pragma unroll
      for (int j = 0; j < WFN; j++){
        acc[i][j] = mfma_bf16(a1[i], b1[j], acc[i][j]);
        acc[i][j] = mfma_bf16(a1[i], b2[j], acc[i][j]);
        acc[i][j] = mfma_bf16(a2[i], b1[j], acc[i][j]);
      }
  }
  asm volatile("s_nop 7\n\ts_nop 7" ::);

  const int r0 = (lane >> 4) << 2;
  #pragma unroll
  for (int j = 0; j < WFN; j++){
    int col = n0 + j * 16 + lrow;
    if (col < N){
      float bv_ = BIAS ? bias[col] : 0.f;
      #pragma unroll
      for (int i = 0; i < WFM; i++)
        #pragma unroll
        for (int r = 0; r < 4; r++)
          Cout[(long long)(m0 + i * 16 + r0 + r) * ldc + col] = acc[i][j][r] + bv_;
    }
  }
}

// 3-limb split GEMM (fp32-exact, err ~3e-8): gx (z=0) and gh (z=1) in one launch.
template<int WFM, int WFN>
__global__ __launch_bounds__(256, 2) void gemm_split3_dual(
    const ushort* __restrict__ A10, const ushort* __restrict__ A20, const ushort* __restrict__ A30,
    const ushort* __restrict__ B10, const ushort* __restrict__ B20, const ushort* __restrict__ B30,
    float* __restrict__ C0, const float* __restrict__ bias0,
    const ushort* __restrict__ A11, const ushort* __restrict__ A21, const ushort* __restrict__ A31,
    const ushort* __restrict__ B11, const ushort* __restrict__ B21, const ushort* __restrict__ B31,
    float* __restrict__ C1, const float* __restrict__ bias1,
    int M, int N, int K)
{
  const ushort *A1,*A2,*A3,*B1,*B2,*B3; float* Cout; const float* bias;
  if (blockIdx.z == 0){ A1=A10;A2=A20;A3=A30;B1=B10;B2=B20;B3=B30;Cout=C0;bias=bias0; }
  else                { A1=A11;A2=A21;A3=A31;B1=B11;B2=B21;B3=B31;Cout=C1;bias=bias1; }

  const int tid = threadIdx.x;
  const int wave = tid >> 6, lane = tid & 63;
  const int wy = wave >> 1, wx = wave & 1;
  const int lrow = lane & 15, kof = (lane >> 4) << 3;
  const int m0 = blockIdx.x * (WFM * 32) + wy * (WFM * 16);
  const int n0 = blockIdx.y * (WFN * 32) + wx * (WFN * 16);

  v4f acc[WFM][WFN];
  #pragma unroll
  for (int i = 0; i < WFM; i++)
    #pragma unroll
    for (int j = 0; j < WFN; j++) acc[i][j] = (v4f)0.f;

  size_t aoff[WFM], boff[WFN];
  #pragma unroll
  for (int i = 0; i < WFM; i++) aoff[i] = (size_t)(m0 + i * 16 + lrow) * K + kof;
  #pragma unroll
  for (int j = 0; j < WFN; j++) boff[j] = (size_t)(n0 + j * 16 + lrow) * K + kof;

  for (int kk = 0; kk < K; kk += 32){
    v8s a1[WFM], a2[WFM], a3[WFM], b1[WFN], b2[WFN], b3[WFN];
    #pragma unroll
    for (int i = 0; i < WFM; i++){
      a1[i] = *(const v8s*)(A1 + aoff[i] + kk);
      a2[i] = *(const v8s*)(A2 + aoff[i] + kk);
      a3[i] = *(const v8s*)(A3 + aoff[i] + kk);
    }
    #pragma unroll
    for (int j = 0; j < WFN; j++){
      b1[j] = *(const v8s*)(B1 + boff[j] + kk);
      b2[j] = *(const v8s*)(B2 + boff[j] + kk);
      b3[j] = *(const v8s*)(B3 + boff[j] + kk);
    }
    #pragma unroll
    for (int i = 0; i < WFM; i++)
      #pragma unroll
      for (int j = 0; j < WFN; j++){
        acc[i][j] = mfma_bf16(a1[i], b1[j], acc[i][j]);   // 2^0
        acc[i][j] = mfma_bf16(a1[i], b2[j], acc[i][j]);   // 2^-9
        acc[i][j] = mfma_bf16(a2[i], b1[j], acc[i][j]);
        acc[i][j] = mfma_bf16(a1[i], b3[j], acc[i][j]);   // 2^-18
        acc[i][j] = mfma_bf16(a2[i], b2[j], acc[i][j]);
        acc[i][j] = mfma_bf16(a3[i], b1[j], acc[i][j]);
      }
  }
  asm volatile("s_nop 7\n\ts_nop 7" ::);

  const int r0 = (lane >> 4) << 2;
  #pragma unroll
  for (int j = 0; j < WFN; j++){
    int col = n0 + j * 16 + lrow;
    float bv_ = bias[col];
    #pragma unroll
    for (int i = 0; i < WFM; i++)
      #pragma unroll
      for (int r = 0; r < 4; r++)
        Cout[(size_t)(m0 + i * 16 + r0 + r) * N + col] = acc[i][j][r] + bv_;
  }
}

// ---------------- attention / decode ----------------

// FUSED per-step attention: e -> softmax -> context, one block per b (512 thr).
// Numerics are BIT-IDENTICAL to the previous attn_e_part + ctx_soft pair:
//  - e[w]: each wave computes 16 w-rows with the identical 64-lane x 8-h
//    sequential-sum + shfl_down tree (per-w op order unchanged).
//  - softmax: identical 128-wide shared-mem max/sum trees (s=64..1).
//  - context: identical per-c fp64 fma loop over w=0..127.
__global__ __launch_bounds__(512) void attn_ctx(
    const float* __restrict__ Hp, const float* __restrict__ ph,
    const float* __restrict__ sw, const float* __restrict__ inputs,
    ushort* __restrict__ c1, ushort* __restrict__ c2, ushort* __restrict__ c3)
{
  __shared__ float ph_s[512], sw_s[512], e_s[128], red[128], a_s[128];
  const int b = blockIdx.x, tid = threadIdx.x;
  ph_s[tid] = ph[b * 512 + tid];
  sw_s[tid] = sw[tid];
  __syncthreads();

  // ---- phase 1: e[w] for w = wv*16 .. wv*16+15 (8 waves x 16 rows) ----
  const int wv = tid >> 6, lane = tid & 63, h0 = lane * 8;
  float phv[8], swv[8];
  #pragma unroll
  for (int j = 0; j < 8; j++){ phv[j] = ph_s[h0 + j]; swv[j] = sw_s[h0 + j]; }
  for (int i = 0; i < 16; i++){
    int w = wv * 16 + i;
    const float* row = Hp + ((size_t)b * 128 + w) * 512 + h0;
    float4 x0 = *(const float4*)row;
    float4 x1 = *(const float4*)(row + 4);
    float xs[8] = {x0.x,x0.y,x0.z,x0.w,x1.x,x1.y,x1.z,x1.w};
    float sum = 0.f;
    #pragma unroll
    for (int j = 0; j < 8; j++) sum += fast_tanh(xs[j] + phv[j]) * swv[j];
    #pragma unroll
    for (int off = 32; off; off >>= 1) sum += __shfl_down(sum, off, 64);
    if (lane == 0) e_s[w] = sum;
  }
  __syncthreads();

  // ---- phase 2: softmax over e_s (identical tree to old ctx_soft) ----
  float v = 0.f, p = 0.f;
  if (tid < 128){ v = e_s[tid]; red[tid] = v; }
  __syncthreads();
  for (int s = 64; s; s >>= 1){ if (tid < s) red[tid] = fmaxf(red[tid], red[tid + s]); __syncthreads(); }
  const float m = red[0]; __syncthreads();
  if (tid < 128){ p = expf(v - m); red[tid] = p; }
  __syncthreads();
  for (int s = 64; s; s >>= 1){ if (tid < s) red[tid] += red[tid + s]; __syncthreads(); }
  const float den = red[0]; __syncthreads();
  if (tid < 128) a_s[tid] = p / den;
  __syncthreads();

  // ---- phase 3: context (fp64 acc, identical loop) -> 3-limb bf16 ----
  const float* base = inputs + (size_t)b * 128 * 512 + tid;   // c = tid
  double acc = 0.0;
  #pragma unroll 8
  for (int w = 0; w < 128; w++) acc = fma((double)a_s[w], (double)base[(size_t)w * 512], acc);
  float x = (float)acc;
  ushort h1 = f2bf(x); float r = x - bf2f(h1);
  ushort h2 = f2bf(r); r -= bf2f(h2);
  const size_t o = (size_t)b * 512 + tid;
  c1[o] = h1; c2[o] = h2; c3[o] = f2bf(r);
}

// GRU elementwise, precise fp32; writes h fp32 + 3-limb bf16 (exactly represents fp32 h).
__global__ __launch_bounds__(512) void gru_kernel(
    const float* __restrict__ gx, const float* __restrict__ gh,
    const float* __restrict__ wihT_oh, const int* __restrict__ tgt,
    const float* __restrict__ h_in, float* __restrict__ h_out,
    ushort* __restrict__ h1, ushort* __restrict__ h2, ushort* __restrict__ h3)
{
  const int b = blockIdx.x, h = threadIdx.x;
  const float* oh = wihT_oh + (size_t)tgt[b] * G3_;
  const size_t g = (size_t)b * G3_;
  float xr = gx[g + h]        + oh[h];
  float xz = gx[g + 512 + h]  + oh[512 + h];
  float xn = gx[g + 1024 + h] + oh[1024 + h];
  float hr = gh[g + h], hz = gh[g + 512 + h], hn = gh[g + 1024 + h];
  float rr = 1.f / (1.f + expf(-(xr + hr)));
  float zz = 1.f / (1.f + expf(-(xz + hz)));
  float nn = tanhf(xn + rr * hn);
  float hp = h_in[(size_t)b * 512 + h];
  float nh = (1.f - zz) * nn + zz * hp;
  const size_t o = (size_t)b * 512 + h;
  h_out[o] = nh;
  ushort l1 = f2bf(nh); float r = nh - bf2f(l1);
  ushort l2 = f2bf(r);  r -= bf2f(l2);
  h1[o] = l1; h2[o] = l2; h3[o] = f2bf(r);
}

// Greedy argmax: probs are ~1e-6-accurate; refine all candidates within 1e-4 of the
// max with exact fp64 logits; ties -> smallest index (jnp.argmax semantics).
__global__ __launch_bounds__(256) void argmax_refine(
    const float* __restrict__ probs_t,   // d_out + t*C, row stride T*C
    const float* __restrict__ h,         // new h fp32 [B,512]
    const float* __restrict__ gen_w, const float* __restrict__ gen_b,
    int* __restrict__ tgt)
{
  const int b = blockIdx.x, tid = threadIdx.x;
  const float* row = probs_t + (size_t)b * ((size_t)T_ * C_);
  __shared__ float h_s[512];
  h_s[tid]       = h[(size_t)b * 512 + tid];
  h_s[tid + 256] = h[(size_t)b * 512 + tid + 256];
  float mx = -1e30f;
  for (int c = tid; c < C_; c += 256) mx = fmaxf(mx, row[c]);
  __shared__ float red[256];
  red[tid] = mx; __syncthreads();
  for (int s = 128; s; s >>= 1){ if (tid < s) red[tid] = fmaxf(red[tid], red[tid + s]); __syncthreads(); }
  const float gmax = red[0];

  double bestv = -1e300; int besti = 0x7fffffff;
  for (int c = tid; c < C_; c += 256){
    if (row[c] >= gmax - 1e-4f){
      const float* wrow = gen_w + (size_t)c * 512;
      double d = (double)gen_b[c];
      for (int k = 0; k < 512; k++) d = fma((double)h_s[k], (double)wrow[k], d);
      if (d > bestv || (d == bestv && c < besti)){ bestv = d; besti = c; }
    }
  }
  __shared__ double rv[256]; __shared__ int ri[256];
  rv[tid] = bestv; ri[tid] = besti; __syncthreads();
  for (int s = 128; s; s >>= 1){
    if (tid < s){
      if (rv[tid + s] > rv[tid] || (rv[tid + s] == rv[tid] && ri[tid + s] < ri[tid])){
        rv[tid] = rv[tid + s]; ri[tid] = ri[tid + s];
      }
    }
    __syncthreads();
  }
  if (tid == 0) tgt[b] = ri[0];
}

// ---------------- host launcher ----------------

extern "C" void kernel_launch(void* const* d_in, const int* in_sizes, int n_in,
                              void* d_out, int out_size, void* d_ws, size_t ws_size,
                              hipStream_t stream)
{
  const float* inputs  = (const float*)d_in[0];
  const float* i2h_w   = (const float*)d_in[1];
  const float* h2h_w   = (const float*)d_in[2];
  const float* h2h_b   = (const float*)d_in[3];
  const float* score_w = (const float*)d_in[4];
  const float* gru_wih = (const float*)d_in[5];
  const float* gru_bih = (const float*)d_in[6];
  const float* gru_whh = (const float*)d_in[7];
  const float* gru_bhh = (const float*)d_in[8];
  const float* gen_w   = (const float*)d_in[9];
  const float* gen_b   = (const float*)d_in[10];
  (void)in_sizes; (void)n_in; (void)out_size; (void)ws_size;

  char* ws = (char*)d_ws;
  size_t off = 0;
  auto alloc = [&](size_t bytes)->char*{
    char* p = ws + off; off += (bytes + 255) & ~(size_t)255; return p;
  };

  float*  Hproj   = (float*) alloc((size_t)B_ * W_ * H_ * 4);      // 67 MB
  ushort* i2h_1   = (ushort*)alloc((size_t)H_ * CIN_ * 2);
  ushort* i2h_2   = (ushort*)alloc((size_t)H_ * CIN_ * 2);
  ushort* h2h_1   = (ushort*)alloc((size_t)H_ * H_ * 2);
  ushort* h2h_2   = (ushort*)alloc((size_t)H_ * H_ * 2);
  ushort* gen_1   = (ushort*)alloc((size_t)C_ * H_ * 2);
  ushort* gen_2   = (ushort*)alloc((size_t)C_ * H_ * 2);
  ushort* wih_1   = (ushort*)alloc((size_t)G3_ * CIN_ * 2);
  ushort* wih_2   = (ushort*)alloc((size_t)G3_ * CIN_ * 2);
  ushort* wih_3   = (ushort*)alloc((size_t)G3_ * CIN_ * 2);
  ushort* whh_1   = (ushort*)alloc((size_t)G3_ * H_ * 2);
  ushort* whh_2   = (ushort*)alloc((size_t)G3_ * H_ * 2);
  ushort* whh_3   = (ushort*)alloc((size_t)G3_ * H_ * 2);
  float*  wihT_oh = (float*) alloc((size_t)C_ * G3_ * 4);          // 40.7 MB
  float*  ph      = (float*) alloc((size_t)B_ * H_ * 4);
  ushort* ctx_1   = (ushort*)alloc((size_t)B_ * CIN_ * 2);
  ushort* ctx_2   = (ushort*)alloc((size_t)B_ * CIN_ * 2);
  ushort* ctx_3   = (ushort*)alloc((size_t)B_ * CIN_ * 2);
  float*  gx      = (float*) alloc((size_t)B_ * G3_ * 4);
  float*  gh      = (float*) alloc((size_t)B_ * G3_ * 4);
  // zero-init group (contiguous): h_a, h_b, h limbs, tgt
  char*   zbase = ws + off;
  float*  h_a   = (float*) alloc((size_t)B_ * H_ * 4);
  float*  h_b   = (float*) alloc((size_t)B_ * H_ * 4);
  ushort* h_1   = (ushort*)alloc((size_t)B_ * H_ * 2);
  ushort* h_2   = (ushort*)alloc((size_t)B_ * H_ * 2);
  ushort* h_3   = (ushort*)alloc((size_t)B_ * H_ * 2);
  int*    tgt   = (int*)   alloc((size_t)B_ * 4);
  size_t zbytes = (size_t)((ws + off) - zbase);
  hipMemsetAsync(zbase, 0, zbytes, stream);

  int n;
  n = H_ * CIN_; cvt_split2<<<(n/4 + 255)/256, 256, 0, stream>>>(i2h_w, i2h_1, i2h_2, n);
  n = H_ * H_;   cvt_split2<<<(n/4 + 255)/256, 256, 0, stream>>>(h2h_w, h2h_1, h2h_2, n);
  n = C_ * H_;   cvt_split2<<<(n/4 + 255)/256, 256, 0, stream>>>(gen_w, gen_1, gen_2, n);
  n = G3_ * H_;  cvt_split3<<<(n/4 + 255)/256, 256, 0, stream>>>(gru_whh, whh_1, whh_2, whh_3, n);
  pack_wih_split3<<<(G3_ * CIN_) / 256, 256, 0, stream>>>(gru_wih, wih_1, wih_2, wih_3);
  transpose_oh<<<dim3((C_ + 31)/32, G3_/32), 256, 0, stream>>>(gru_wih, wihT_oh);

  // Hproj (fp32 out), M=32768 N=512 K=512, 128x128 tiles
  gemm_hproj<4,4><<<dim3((B_*W_)/128, H_/128), 256, 0, stream>>>(
      inputs, i2h_1, i2h_2, Hproj, B_*W_, H_, CIN_);

  float* probs = (float*)d_out;
  float* hin = h_a; float* hout = h_b;
  for (int t = 0; t < T_; ++t){
    gemm_split2<2,2,true><<<dim3(B_/64, H_/64), 256, 0, stream>>>(
        h_1, h_2, h2h_1, h2h_2, ph, h2h_b, B_, H_, H_, H_);
    attn_ctx<<<B_, 512, 0, stream>>>(Hproj, ph, score_w, inputs, ctx_1, ctx_2, ctx_3);
    gemm_split3_dual<2,2><<<dim3(B_/64, G3_/64, 2), 256, 0, stream>>>(
        ctx_1, ctx_2, ctx_3, wih_1, wih_2, wih_3, gx, gru_bih,
        h_1,  h_2,  h_3,  whh_1, whh_2, whh_3, gh, gru_bhh,
        B_, G3_, CIN_);
    gru_kernel<<<B_, 512, 0, stream>>>(gx, gh, wihT_oh, tgt, hin, hout, h_1, h_2, h_3);
    gemm_split2<2,2,true><<<dim3(B_/64, (C_ + 63)/64), 256, 0, stream>>>(
        h_1, h_2, gen_1, gen_2, probs + (size_t)t * C_, gen_b, B_, C_, H_, (long long)T_ * C_);
    argmax_refine<<<B_, 256, 0, stream>>>(probs + (size_t)t * C_, hout, gen_w, gen_b, tgt);
    float* tmp = hin; hin = hout; hout = tmp;
  }
}

// Round 9
// 3602.091 us; speedup vs baseline: 1.0129x; 1.0129x over previous
//
#include <hip/hip_runtime.h>
#include <hip/hip_bf16.h>
#include <stdint.h>

// Problem constants (batch_max_length=25 fixed by harness input).
#define B_   256
#define W_   128
#define CIN_ 512
#define H_   512
#define C_   6625
#define G3_  1536   // 3*H
#define T_   25
#define XH_  7137   // CIN + C

typedef short v8s __attribute__((ext_vector_type(8)));   // 8 bf16 in 4 VGPRs
typedef float v4f __attribute__((ext_vector_type(4)));   // MFMA 16x16 accumulator

__device__ __forceinline__ float bf2f(ushort u){ return __uint_as_float(((uint32_t)u) << 16); }
__device__ __forceinline__ ushort f2bf(float f){
  uint32_t x = __float_as_uint(f);
  x += 0x7fffu + ((x >> 16) & 1u);   // RNE
  return (ushort)(x >> 16);
}
// fast tanh — used ONLY in the attention e-path (errors dilute ~100x via softmax/context).
__device__ __forceinline__ float fast_tanh(float x){
  x = fminf(15.f, fmaxf(-15.f, x));
  float u = __expf(2.f * x);
  return (u - 1.f) * __frcp_rn(u + 1.f);
}

// MFMA 16x16x32 bf16 via inline asm.
// A,B: 8 contiguous bf16 per lane at row (lane&15), k-offset 8*(lane>>4).
// D/C: col = lane&15, row = (lane>>4)*4 + reg  [learn_hip m89].
__device__ __forceinline__ v4f mfma_bf16(v8s a, v8s b, v4f c){
  asm volatile("v_mfma_f32_16x16x32_bf16 %0, %1, %2, %0" : "+v"(c) : "v"(a), "v"(b));
  return c;
}

// ---------------- conversion / packing ----------------

// fp32 -> 2-limb bf16 (hi+lo); rep err ~ x*2^-18
__global__ void cvt_split2(const float* __restrict__ in, ushort* __restrict__ a1,
                           ushort* __restrict__ a2, int n){
  int idx = (blockIdx.x * blockDim.x + threadIdx.x) * 4;
  if (idx < n){
    float4 v = *(const float4*)(in + idx);
    ushort4 h1, h2; float x, r;
    x=v.x; h1.x=f2bf(x); r=x-bf2f(h1.x); h2.x=f2bf(r);
    x=v.y; h1.y=f2bf(x); r=x-bf2f(h1.y); h2.y=f2bf(r);
    x=v.z; h1.z=f2bf(x); r=x-bf2f(h1.z); h2.z=f2bf(r);
    x=v.w; h1.w=f2bf(x); r=x-bf2f(h1.w); h2.w=f2bf(r);
    *(ushort4*)(a1 + idx) = h1;
    *(ushort4*)(a2 + idx) = h2;
  }
}

// fp32 -> 3-limb bf16; 3x8 mantissa bits = fp32-exact (rep err ~ x*2^-27)
__global__ void cvt_split3(const float* __restrict__ in, ushort* __restrict__ a1,
                           ushort* __restrict__ a2, ushort* __restrict__ a3, int n){
  int idx = (blockIdx.x * blockDim.x + threadIdx.x) * 4;
  if (idx < n){
    float4 v = *(const float4*)(in + idx);
    ushort4 h1, h2, h3; float x, r;
    #define SPL(F) x=v.F; h1.F=f2bf(x); r=x-bf2f(h1.F); h2.F=f2bf(r); r-=bf2f(h2.F); h3.F=f2bf(r);
    SPL(x) SPL(y) SPL(z) SPL(w)
    #undef SPL
    *(ushort4*)(a1 + idx) = h1;
    *(ushort4*)(a2 + idx) = h2;
    *(ushort4*)(a3 + idx) = h3;
  }
}

// gru_wih[:, :CIN] -> 3-limb bf16 [G3][CIN]
__global__ void pack_wih_split3(const float* __restrict__ wih, ushort* __restrict__ a1,
                                ushort* __restrict__ a2, ushort* __restrict__ a3){
  int idx = blockIdx.x * 256 + threadIdx.x;       // total G3_*CIN_
  int g = idx >> 9, k = idx & 511;
  float x = wih[(size_t)g * XH_ + k];
  ushort h1 = f2bf(x); float r = x - bf2f(h1);
  ushort h2 = f2bf(r); r -= bf2f(h2);
  a1[idx] = h1; a2[idx] = h2; a3[idx] = f2bf(r);
}

// gru_wih[:, CIN:].T -> fp32 [C][G3] (coalesced per-step one-hot gathers)
__global__ void transpose_oh(const float* __restrict__ wih, float* __restrict__ out){
  __shared__ float t[32][33];
  int c0 = blockIdx.x * 32, g0 = blockIdx.y * 32;
  int tx = threadIdx.x & 31, ty = threadIdx.x >> 5;   // 256 thr = 32x8
  for (int r = ty; r < 32; r += 8){
    int c = c0 + tx;
    t[r][tx] = (c < C_) ? wih[(size_t)(g0 + r) * XH_ + CIN_ + c] : 0.f;
  }
  __syncthreads();
  for (int r = ty; r < 32; r += 8){
    int c = c0 + r;
    if (c < C_) out[(size_t)c * G3_ + (g0 + tx)] = t[tx][r];
  }
}

// -------- GEMMs: C[M,N] = A[M,K] * B[N,K]^T (+bias), fp32 out --------
// 4 waves (2x2); wave tile (WFM*16)x(WFN*16); direct global->register fragments.

// Hproj: A fp32 (split2 on the fly), B split2 pre-packed. 3 products.
template<int WFM, int WFN>
__global__ __launch_bounds__(256, 2) void gemm_hproj(
    const float* __restrict__ A, const ushort* __restrict__ B1,
    const ushort* __restrict__ B2, float* __restrict__ Cout,
    int M, int N, int K)
{
  const int tid = threadIdx.x;
  const int wave = tid >> 6, lane = tid & 63;
  const int wy = wave >> 1, wx = wave & 1;
  const int lrow = lane & 15, kof = (lane >> 4) << 3;
  const int m0 = blockIdx.x * (WFM * 32) + wy * (WFM * 16);
  const int n0 = blockIdx.y * (WFN * 32) + wx * (WFN * 16);

  v4f acc[WFM][WFN];
  #pragma unroll
  for (int i = 0; i < WFM; i++)
    #pragma unroll
    for (int j = 0; j < WFN; j++) acc[i][j] = (v4f)0.f;

  const float* Ap[WFM];
  #pragma unroll
  for (int i = 0; i < WFM; i++) Ap[i] = A + (size_t)(m0 + i * 16 + lrow) * K + kof;
  size_t boff[WFN];
  #pragma unroll
  for (int j = 0; j < WFN; j++) boff[j] = (size_t)(n0 + j * 16 + lrow) * K + kof;

  for (int kk = 0; kk < K; kk += 32){
    v8s a1[WFM], a2[WFM], b1[WFN], b2[WFN];
    #pragma unroll
    for (int i = 0; i < WFM; i++){
      float4 x0 = *(const float4*)(Ap[i] + kk);
      float4 x1 = *(const float4*)(Ap[i] + kk + 4);
      float xs[8] = {x0.x,x0.y,x0.z,x0.w,x1.x,x1.y,x1.z,x1.w};
      #pragma unroll
      for (int q = 0; q < 8; q++){
        ushort h = f2bf(xs[q]);
        a1[i][q] = (short)h;
        a2[i][q] = (short)f2bf(xs[q] - bf2f(h));
      }
    }
    #pragma unroll
    for (int j = 0; j < WFN; j++){
      b1[j] = *(const v8s*)(B1 + boff[j] + kk);
      b2[j] = *(const v8s*)(B2 + boff[j] + kk);
    }
    #pragma unroll
    for (int i = 0; i < WFM; i++)
      #pragma unroll
      for (int j = 0; j < WFN; j++){
        acc[i][j] = mfma_bf16(a1[i], b1[j], acc[i][j]);
        acc[i][j] = mfma_bf16(a1[i], b2[j], acc[i][j]);
        acc[i][j] = mfma_bf16(a2[i], b1[j], acc[i][j]);
      }
  }
  asm volatile("s_nop 7\n\ts_nop 7" ::);

  const int r0 = (lane >> 4) << 2;
  #pragma unroll
  for (int j = 0; j < WFN; j++){
    int col = n0 + j * 16 + lrow;
    #pragma unroll
    for (int i = 0; i < WFM; i++)
      #pragma unroll
      for (int r = 0; r < 4; r++)
        Cout[(size_t)(m0 + i * 16 + r0 + r) * N + col] = acc[i][j][r];
  }
}

// 2-limb split GEMM (err ~1e-6): ph, gen-probs.
template<int WFM, int WFN, bool BIAS>
__global__ __launch_bounds__(256, 2) void gemm_split2(
    const ushort* __restrict__ A1, const ushort* __restrict__ A2,
    const ushort* __restrict__ B1, const ushort* __restrict__ B2,
    float* __restrict__ Cout, const float* __restrict__ bias,
    int M, int N, int K, long long ldc)
{
  const int tid = threadIdx.x;
  const int wave = tid >> 6, lane = tid & 63;
  const int wy = wave >> 1, wx = wave & 1;
  const int lrow = lane & 15, kof = (lane >> 4) << 3;
  const int m0 = blockIdx.x * (WFM * 32) + wy * (WFM * 16);
  const int n0 = blockIdx.y * (WFN * 32) + wx * (WFN * 16);

  v4f acc[WFM][WFN];
  #pragma unroll
  for (int i = 0; i < WFM; i++)
    #pragma unroll
    for (int j = 0; j < WFN; j++) acc[i][j] = (v4f)0.f;

  size_t aoff[WFM], boff[WFN];
  #pragma unroll
  for (int i = 0; i < WFM; i++) aoff[i] = (size_t)(m0 + i * 16 + lrow) * K + kof;
  #pragma unroll
  for (int j = 0; j < WFN; j++){
    int r = n0 + j * 16 + lrow; if (r >= N) r = N - 1;
    boff[j] = (size_t)r * K + kof;
  }

  for (int kk = 0; kk < K; kk += 32){
    v8s a1[WFM], a2[WFM], b1[WFN], b2[WFN];
    #pragma unroll
    for (int i = 0; i < WFM; i++){
      a1[i] = *(const v8s*)(A1 + aoff[i] + kk);
      a2[i] = *(const v8s*)(A2 + aoff[i] + kk);
    }
    #pragma unroll
    for (int j = 0; j < WFN; j++){
      b1[j] = *(const v8s*)(B1 + boff[j] + kk);
      b2[j] = *(const v8s*)(B2 + boff[j] + kk);
    }
    #pragma unroll
    for (int i = 0; i < WFM; i++)
      #pragma unroll
      for (int j = 0; j < WFN; j++){
        acc[i][j] = mfma_bf16(a1[i], b1[j], acc[i][j]);
        acc[i][j] = mfma_bf16(a1[i], b2[j], acc[i][j]);
        acc[i][j] = mfma_bf16(a2[i], b1[j], acc[i][j]);
      }
  }
  asm volatile("s_nop 7\n\ts_nop 7" ::);

  const int r0 = (lane >> 4) << 2;
  #pragma unroll
  for (int j = 0; j < WFN; j++){
    int col = n0 + j * 16 + lrow;
    if (col < N){
      float bv_ = BIAS ? bias[col] : 0.f;
      #pragma unroll
      for (int i = 0; i < WFM; i++)
        #pragma unroll
        for (int r = 0; r < 4; r++)
          Cout[(long long)(m0 + i * 16 + r0 + r) * ldc + col] = acc[i][j][r] + bv_;
    }
  }
}

// 3-limb split GEMM (fp32-exact, err ~3e-8): gx (z=0) and gh (z=1) in one launch.
template<int WFM, int WFN>
__global__ __launch_bounds__(256, 2) void gemm_split3_dual(
    const ushort* __restrict__ A10, const ushort* __restrict__ A20, const ushort* __restrict__ A30,
    const ushort* __restrict__ B10, const ushort* __restrict__ B20, const ushort* __restrict__ B30,
    float* __restrict__ C0, const float* __restrict__ bias0,
    const ushort* __restrict__ A11, const ushort* __restrict__ A21, const ushort* __restrict__ A31,
    const ushort* __restrict__ B11, const ushort* __restrict__ B21, const ushort* __restrict__ B31,
    float* __restrict__ C1, const float* __restrict__ bias1,
    int M, int N, int K)
{
  const ushort *A1,*A2,*A3,*B1,*B2,*B3; float* Cout; const float* bias;
  if (blockIdx.z == 0){ A1=A10;A2=A20;A3=A30;B1=B10;B2=B20;B3=B30;Cout=C0;bias=bias0; }
  else                { A1=A11;A2=A21;A3=A31;B1=B11;B2=B21;B3=B31;Cout=C1;bias=bias1; }

  const int tid = threadIdx.x;
  const int wave = tid >> 6, lane = tid & 63;
  const int wy = wave >> 1, wx = wave & 1;
  const int lrow = lane & 15, kof = (lane >> 4) << 3;
  const int m0 = blockIdx.x * (WFM * 32) + wy * (WFM * 16);
  const int n0 = blockIdx.y * (WFN * 32) + wx * (WFN * 16);

  v4f acc[WFM][WFN];
  #pragma unroll
  for (int i = 0; i < WFM; i++)
    #pragma unroll
    for (int j = 0; j < WFN; j++) acc[i][j] = (v4f)0.f;

  size_t aoff[WFM], boff[WFN];
  #pragma unroll
  for (int i = 0; i < WFM; i++) aoff[i] = (size_t)(m0 + i * 16 + lrow) * K + kof;
  #pragma unroll
  for (int j = 0; j < WFN; j++) boff[j] = (size_t)(n0 + j * 16 + lrow) * K + kof;

  for (int kk = 0; kk < K; kk += 32){
    v8s a1[WFM], a2[WFM], a3[WFM], b1[WFN], b2[WFN], b3[WFN];
    #pragma unroll
    for (int i = 0; i < WFM; i++){
      a1[i] = *(const v8s*)(A1 + aoff[i] + kk);
      a2[i] = *(const v8s*)(A2 + aoff[i] + kk);
      a3[i] = *(const v8s*)(A3 + aoff[i] + kk);
    }
    #pragma unroll
    for (int j = 0; j < WFN; j++){
      b1[j] = *(const v8s*)(B1 + boff[j] + kk);
      b2[j] = *(const v8s*)(B2 + boff[j] + kk);
      b3[j] = *(const v8s*)(B3 + boff[j] + kk);
    }
    #pragma unroll
    for (int i = 0; i < WFM; i++)
      #pragma unroll
      for (int j = 0; j < WFN; j++){
        acc[i][j] = mfma_bf16(a1[i], b1[j], acc[i][j]);   // 2^0
        acc[i][j] = mfma_bf16(a1[i], b2[j], acc[i][j]);   // 2^-9
        acc[i][j] = mfma_bf16(a2[i], b1[j], acc[i][j]);
        acc[i][j] = mfma_bf16(a1[i], b3[j], acc[i][j]);   // 2^-18
        acc[i][j] = mfma_bf16(a2[i], b2[j], acc[i][j]);
        acc[i][j] = mfma_bf16(a3[i], b1[j], acc[i][j]);
      }
  }
  asm volatile("s_nop 7\n\ts_nop 7" ::);

  const int r0 = (lane >> 4) << 2;
  #pragma unroll
  for (int j = 0; j < WFN; j++){
    int col = n0 + j * 16 + lrow;
    float bv_ = bias[col];
    #pragma unroll
    for (int i = 0; i < WFM; i++)
      #pragma unroll
      for (int r = 0; r < 4; r++)
        Cout[(size_t)(m0 + i * 16 + r0 + r) * N + col] = acc[i][j][r] + bv_;
  }
}

// ---------------- attention / decode ----------------

// FUSED per-step attention: e -> softmax -> context. One block per b,
// 1024 threads (16 waves) for latency hiding on the L3-resident streams.
//  - phase 1: 16 waves x 8 w-rows, identical per-w 64-lane x 8-h sum + shfl tree.
//  - phase 2: identical 128-wide shared-mem softmax trees.
//  - phase 3: w-range split in two (tid>>9); two fp64 partials combined in LDS
//    (summation-order delta ~1e-16 — trajectory-safe).
__global__ __launch_bounds__(1024, 4) void attn_ctx(
    const float* __restrict__ Hp, const float* __restrict__ ph,
    const float* __restrict__ sw, const float* __restrict__ inputs,
    ushort* __restrict__ c1, ushort* __restrict__ c2, ushort* __restrict__ c3)
{
  __shared__ float ph_s[512], sw_s[512], e_s[128], red[128], a_s[128];
  __shared__ double part[2][512];
  const int b = blockIdx.x, tid = threadIdx.x;
  if (tid < 512){ ph_s[tid] = ph[b * 512 + tid]; sw_s[tid] = sw[tid]; }
  __syncthreads();

  // ---- phase 1: e[w] for w = wv*8 .. wv*8+7 (16 waves x 8 rows) ----
  const int wv = tid >> 6, lane = tid & 63, h0 = lane * 8;
  float phv[8], swv[8];
  #pragma unroll
  for (int j = 0; j < 8; j++){ phv[j] = ph_s[h0 + j]; swv[j] = sw_s[h0 + j]; }
  #pragma unroll
  for (int i = 0; i < 8; i++){
    int w = wv * 8 + i;
    const float* row = Hp + ((size_t)b * 128 + w) * 512 + h0;
    float4 x0 = *(const float4*)row;
    float4 x1 = *(const float4*)(row + 4);
    float xs[8] = {x0.x,x0.y,x0.z,x0.w,x1.x,x1.y,x1.z,x1.w};
    float sum = 0.f;
    #pragma unroll
    for (int j = 0; j < 8; j++) sum += fast_tanh(xs[j] + phv[j]) * swv[j];
    #pragma unroll
    for (int off = 32; off; off >>= 1) sum += __shfl_down(sum, off, 64);
    if (lane == 0) e_s[w] = sum;
  }
  __syncthreads();

  // ---- phase 2: softmax over e_s (identical 128-wide trees) ----
  float v = 0.f, p = 0.f;
  if (tid < 128){ v = e_s[tid]; red[tid] = v; }
  __syncthreads();
  for (int s = 64; s; s >>= 1){ if (tid < s) red[tid] = fmaxf(red[tid], red[tid + s]); __syncthreads(); }
  const float m = red[0]; __syncthreads();
  if (tid < 128){ p = expf(v - m); red[tid] = p; }
  __syncthreads();
  for (int s = 64; s; s >>= 1){ if (tid < s) red[tid] += red[tid + s]; __syncthreads(); }
  const float den = red[0]; __syncthreads();
  if (tid < 128) a_s[tid] = p / den;
  __syncthreads();

  // ---- phase 3: context (fp64 acc, w split in two halves) -> 3-limb bf16 ----
  const int c = tid & 511, half = tid >> 9;
  const float* base = inputs + (size_t)b * 128 * 512 + c;
  double acc = 0.0;
  const int w0 = half * 64;
  #pragma unroll 8
  for (int w = w0; w < w0 + 64; w++) acc = fma((double)a_s[w], (double)base[(size_t)w * 512], acc);
  part[half][c] = acc;
  __syncthreads();
  if (tid < 512){
    double tot = part[0][tid] + part[1][tid];
    float x = (float)tot;
    ushort h1 = f2bf(x); float r = x - bf2f(h1);
    ushort h2 = f2bf(r); r -= bf2f(h2);
    const size_t o = (size_t)b * 512 + tid;
    c1[o] = h1; c2[o] = h2; c3[o] = f2bf(r);
  }
}

// GRU elementwise, precise fp32; writes h fp32 + 3-limb bf16 (exactly represents fp32 h).
__global__ __launch_bounds__(512) void gru_kernel(
    const float* __restrict__ gx, const float* __restrict__ gh,
    const float* __restrict__ wihT_oh, const int* __restrict__ tgt,
    const float* __restrict__ h_in, float* __restrict__ h_out,
    ushort* __restrict__ h1, ushort* __restrict__ h2, ushort* __restrict__ h3)
{
  const int b = blockIdx.x, h = threadIdx.x;
  const float* oh = wihT_oh + (size_t)tgt[b] * G3_;
  const size_t g = (size_t)b * G3_;
  float xr = gx[g + h]        + oh[h];
  float xz = gx[g + 512 + h]  + oh[512 + h];
  float xn = gx[g + 1024 + h] + oh[1024 + h];
  float hr = gh[g + h], hz = gh[g + 512 + h], hn = gh[g + 1024 + h];
  float rr = 1.f / (1.f + expf(-(xr + hr)));
  float zz = 1.f / (1.f + expf(-(xz + hz)));
  float nn = tanhf(xn + rr * hn);
  float hp = h_in[(size_t)b * 512 + h];
  float nh = (1.f - zz) * nn + zz * hp;
  const size_t o = (size_t)b * 512 + h;
  h_out[o] = nh;
  ushort l1 = f2bf(nh); float r = nh - bf2f(l1);
  ushort l2 = f2bf(r);  r -= bf2f(l2);
  h1[o] = l1; h2[o] = l2; h3[o] = f2bf(r);
}

// Greedy argmax: probs are ~1e-6-accurate; refine all candidates within 1e-4 of the
// max with exact fp64 logits; ties -> smallest index (jnp.argmax semantics).
__global__ __launch_bounds__(256) void argmax_refine(
    const float* __restrict__ probs_t,   // d_out + t*C, row stride T*C
    const float* __restrict__ h,         // new h fp32 [B,512]
    const float* __restrict__ gen_w, const float* __restrict__ gen_b,
    int* __restrict__ tgt)
{
  const int b = blockIdx.x, tid = threadIdx.x;
  const float* row = probs_t + (size_t)b * ((size_t)T_ * C_);
  __shared__ float h_s[512];
  h_s[tid]       = h[(size_t)b * 512 + tid];
  h_s[tid + 256] = h[(size_t)b * 512 + tid + 256];
  float mx = -1e30f;
  for (int c = tid; c < C_; c += 256) mx = fmaxf(mx, row[c]);
  __shared__ float red[256];
  red[tid] = mx; __syncthreads();
  for (int s = 128; s; s >>= 1){ if (tid < s) red[tid] = fmaxf(red[tid], red[tid + s]); __syncthreads(); }
  const float gmax = red[0];

  double bestv = -1e300; int besti = 0x7fffffff;
  for (int c = tid; c < C_; c += 256){
    if (row[c] >= gmax - 1e-4f){
      const float* wrow = gen_w + (size_t)c * 512;
      double d = (double)gen_b[c];
      for (int k = 0; k < 512; k++) d = fma((double)h_s[k], (double)wrow[k], d);
      if (d > bestv || (d == bestv && c < besti)){ bestv = d; besti = c; }
    }
  }
  __shared__ double rv[256]; __shared__ int ri[256];
  rv[tid] = bestv; ri[tid] = besti; __syncthreads();
  for (int s = 128; s; s >>= 1){
    if (tid < s){
      if (rv[tid + s] > rv[tid] || (rv[tid + s] == rv[tid] && ri[tid + s] < ri[tid])){
        rv[tid] = rv[tid + s]; ri[tid] = ri[tid + s];
      }
    }
    __syncthreads();
  }
  if (tid == 0) tgt[b] = ri[0];
}

// ---------------- host launcher ----------------

extern "C" void kernel_launch(void* const* d_in, const int* in_sizes, int n_in,
                              void* d_out, int out_size, void* d_ws, size_t ws_size,
                              hipStream_t stream)
{
  const float* inputs  = (const float*)d_in[0];
  const float* i2h_w   = (const float*)d_in[1];
  const float* h2h_w   = (const float*)d_in[2];
  const float* h2h_b   = (const float*)d_in[3];
  const float* score_w = (const float*)d_in[4];
  const float* gru_wih = (const float*)d_in[5];
  const float* gru_bih = (const float*)d_in[6];
  const float* gru_whh = (const float*)d_in[7];
  const float* gru_bhh = (const float*)d_in[8];
  const float* gen_w   = (const float*)d_in[9];
  const float* gen_b   = (const float*)d_in[10];
  (void)in_sizes; (void)n_in; (void)out_size; (void)ws_size;

  char* ws = (char*)d_ws;
  size_t off = 0;
  auto alloc = [&](size_t bytes)->char*{
    char* p = ws + off; off += (bytes + 255) & ~(size_t)255; return p;
  };

  float*  Hproj   = (float*) alloc((size_t)B_ * W_ * H_ * 4);      // 67 MB
  ushort* i2h_1   = (ushort*)alloc((size_t)H_ * CIN_ * 2);
  ushort* i2h_2   = (ushort*)alloc((size_t)H_ * CIN_ * 2);
  ushort* h2h_1   = (ushort*)alloc((size_t)H_ * H_ * 2);
  ushort* h2h_2   = (ushort*)alloc((size_t)H_ * H_ * 2);
  ushort* gen_1   = (ushort*)alloc((size_t)C_ * H_ * 2);
  ushort* gen_2   = (ushort*)alloc((size_t)C_ * H_ * 2);
  ushort* wih_1   = (ushort*)alloc((size_t)G3_ * CIN_ * 2);
  ushort* wih_2   = (ushort*)alloc((size_t)G3_ * CIN_ * 2);
  ushort* wih_3   = (ushort*)alloc((size_t)G3_ * CIN_ * 2);
  ushort* whh_1   = (ushort*)alloc((size_t)G3_ * H_ * 2);
  ushort* whh_2   = (ushort*)alloc((size_t)G3_ * H_ * 2);
  ushort* whh_3   = (ushort*)alloc((size_t)G3_ * H_ * 2);
  float*  wihT_oh = (float*) alloc((size_t)C_ * G3_ * 4);          // 40.7 MB
  float*  ph      = (float*) alloc((size_t)B_ * H_ * 4);
  ushort* ctx_1   = (ushort*)alloc((size_t)B_ * CIN_ * 2);
  ushort* ctx_2   = (ushort*)alloc((size_t)B_ * CIN_ * 2);
  ushort* ctx_3   = (ushort*)alloc((size_t)B_ * CIN_ * 2);
  float*  gx      = (float*) alloc((size_t)B_ * G3_ * 4);
  float*  gh      = (float*) alloc((size_t)B_ * G3_ * 4);
  // zero-init group (contiguous): h_a, h_b, h limbs, tgt
  char*   zbase = ws + off;
  float*  h_a   = (float*) alloc((size_t)B_ * H_ * 4);
  float*  h_b   = (float*) alloc((size_t)B_ * H_ * 4);
  ushort* h_1   = (ushort*)alloc((size_t)B_ * H_ * 2);
  ushort* h_2   = (ushort*)alloc((size_t)B_ * H_ * 2);
  ushort* h_3   = (ushort*)alloc((size_t)B_ * H_ * 2);
  int*    tgt   = (int*)   alloc((size_t)B_ * 4);
  size_t zbytes = (size_t)((ws + off) - zbase);
  hipMemsetAsync(zbase, 0, zbytes, stream);

  int n;
  n = H_ * CIN_; cvt_split2<<<(n/4 + 255)/256, 256, 0, stream>>>(i2h_w, i2h_1, i2h_2, n);
  n = H_ * H_;   cvt_split2<<<(n/4 + 255)/256, 256, 0, stream>>>(h2h_w, h2h_1, h2h_2, n);
  n = C_ * H_;   cvt_split2<<<(n/4 + 255)/256, 256, 0, stream>>>(gen_w, gen_1, gen_2, n);
  n = G3_ * H_;  cvt_split3<<<(n/4 + 255)/256, 256, 0, stream>>>(gru_whh, whh_1, whh_2, whh_3, n);
  pack_wih_split3<<<(G3_ * CIN_) / 256, 256, 0, stream>>>(gru_wih, wih_1, wih_2, wih_3);
  transpose_oh<<<dim3((C_ + 31)/32, G3_/32), 256, 0, stream>>>(gru_wih, wihT_oh);

  // Hproj (fp32 out), M=32768 N=512 K=512, 128x128 tiles
  gemm_hproj<4,4><<<dim3((B_*W_)/128, H_/128), 256, 0, stream>>>(
      inputs, i2h_1, i2h_2, Hproj, B_*W_, H_, CIN_);

  float* probs = (float*)d_out;
  float* hin = h_a; float* hout = h_b;
  for (int t = 0; t < T_; ++t){
    gemm_split2<2,2,true><<<dim3(B_/64, H_/64), 256, 0, stream>>>(
        h_1, h_2, h2h_1, h2h_2, ph, h2h_b, B_, H_, H_, H_);
    attn_ctx<<<B_, 1024, 0, stream>>>(Hproj, ph, score_w, inputs, ctx_1, ctx_2, ctx_3);
    gemm_split3_dual<2,2><<<dim3(B_/64, G3_/64, 2), 256, 0, stream>>>(
        ctx_1, ctx_2, ctx_3, wih_1, wih_2, wih_3, gx, gru_bih,
        h_1,  h_2,  h_3,  whh_1, whh_2, whh_3, gh, gru_bhh,
        B_, G3_, CIN_);
    gru_kernel<<<B_, 512, 0, stream>>>(gx, gh, wihT_oh, tgt, hin, hout, h_1, h_2, h_3);
    gemm_split2<2,2,true><<<dim3(B_/64, (C_ + 63)/64), 256, 0, stream>>>(
        h_1, h_2, gen_1, gen_2, probs + (size_t)t * C_, gen_b, B_, C_, H_, (long long)T_ * C_);
    argmax_refine<<<B_, 256, 0, stream>>>(probs + (size_t)t * C_, hout, gen_w, gen_b, tgt);
    float* tmp = hin; hin = hout; hout = tmp;
  }
}